// Round 1
// baseline (2024.346 us; speedup 1.0000x reference)
//
#include <hip/hip_runtime.h>
#include <cmath>
#include <cstdint>
#include <cstddef>

#define HID 64
#define NGR 128            // B graphs
#define EDGES 1048576      // B * 1024 * 8
#define EPG 8192           // edges per graph

// ---------------- fill / init ----------------
__global__ __launch_bounds__(256) void fill_kernel(
    float* __restrict__ deg, int* __restrict__ mapping, int n_nodes,
    float* __restrict__ sums, float* __restrict__ ew1,
    float* __restrict__ readout, int total) {
  int stride = gridDim.x * 256;
  for (int i = blockIdx.x * 256 + threadIdx.x; i < total; i += stride) {
    if (i < n_nodes) { deg[i] = 1.0f; mapping[i] = -1; }
    if (i < 128) sums[i] = 0.0f;
    if (ew1 != nullptr && i < EDGES) ew1[i] = 1.0f;
    if (readout != nullptr && i < NGR * 2 * HID) readout[i] = 0.0f;
  }
}

// ---------------- xw = X @ W  (X:[N,DIN], W:[DIN,64]) ----------------
template<int DIN>
__global__ __launch_bounds__(256) void gemm_xw(
    const float* __restrict__ X, const float* __restrict__ W,
    float* __restrict__ XW, int n_nodes) {
  __shared__ float sW[32 * HID];       // 8 KB
  __shared__ float sXT[32 * 132];      // 16.5 KB, X^T tile, pad 4 to break banks
  const int t = threadIdx.x;
  const int cq = t & 15, ng = t >> 4;
  const int c4 = cq * 4;
  const int node0 = blockIdx.x * 128;
  float acc[8][4];
#pragma unroll
  for (int n = 0; n < 8; n++) { acc[n][0]=0.f; acc[n][1]=0.f; acc[n][2]=0.f; acc[n][3]=0.f; }

  for (int k0 = 0; k0 < DIN; k0 += 32) {
    // stage 32 rows of W
    ((float4*)sW)[t * 2 + 0] = ((const float4*)(W + (size_t)k0 * HID))[t * 2 + 0];
    ((float4*)sW)[t * 2 + 1] = ((const float4*)(W + (size_t)k0 * HID))[t * 2 + 1];
    // stage X^T: sXT[i][n] = X[node0+n][k0+i]
    {
      int i4 = (t & 7) * 4;
      int nl = t >> 3;
#pragma unroll
      for (int rep = 0; rep < 4; rep++) {
        int nn = nl + rep * 32;
        int g = node0 + nn;
        float4 v = make_float4(0.f, 0.f, 0.f, 0.f);
        if (g < n_nodes) v = *(const float4*)(X + (size_t)g * DIN + k0 + i4);
        sXT[(i4 + 0) * 132 + nn] = v.x;
        sXT[(i4 + 1) * 132 + nn] = v.y;
        sXT[(i4 + 2) * 132 + nn] = v.z;
        sXT[(i4 + 3) * 132 + nn] = v.w;
      }
    }
    __syncthreads();
#pragma unroll 4
    for (int i = 0; i < 32; i++) {
      float4 w = *(const float4*)(sW + i * HID + c4);
      const float* xr = sXT + i * 132 + ng * 8;
      float4 xa = *(const float4*)xr;
      float4 xb = *(const float4*)(xr + 4);
      float xn[8] = {xa.x, xa.y, xa.z, xa.w, xb.x, xb.y, xb.z, xb.w};
#pragma unroll
      for (int n = 0; n < 8; n++) {
        acc[n][0] = fmaf(xn[n], w.x, acc[n][0]);
        acc[n][1] = fmaf(xn[n], w.y, acc[n][1]);
        acc[n][2] = fmaf(xn[n], w.z, acc[n][2]);
        acc[n][3] = fmaf(xn[n], w.w, acc[n][3]);
      }
    }
    __syncthreads();
  }
#pragma unroll
  for (int n = 0; n < 8; n++) {
    int g = node0 + ng * 8 + n;
    if (g < n_nodes)
      *(float4*)(XW + (size_t)g * HID + c4) =
          make_float4(acc[n][0], acc[n][1], acc[n][2], acc[n][3]);
  }
}

// ---------------- deg += ew scattered to dst ----------------
__global__ __launch_bounds__(256) void deg_acc(
    const int* __restrict__ dst, const float* __restrict__ ew,
    float* __restrict__ deg) {
  int e = blockIdx.x * 256 + threadIdx.x;   // grid sized exactly EDGES/256
  float w = ew[e];
  if (w != 0.0f) atomicAdd(&deg[dst[e]], w);
}

// ---------------- per-graph edge aggregation into LDS ----------------
// block = (graph, channel-quarter).  h[dst] = sum_e norm * xw[src]  (plain store)
__global__ __launch_bounds__(256) void edge_agg(
    const int* __restrict__ src, const int* __restrict__ dst,
    const float* __restrict__ ew, const float* __restrict__ deg,
    const float* __restrict__ xw, float* __restrict__ h, int npg) {
  __shared__ float acc[1024 * 16];   // 64 KB
  int g = blockIdx.x >> 2;
  int c0 = (blockIdx.x & 3) * 16;
  int t = threadIdx.x;
  int nf = npg * 16;
  for (int i = t; i < nf; i += 256) acc[i] = 0.0f;
  __syncthreads();
  int c = t & 15, eg = t >> 4;
  int ebase = g * EPG, nbase = g * npg;
  for (int e0 = eg; e0 < EPG; e0 += 16) {
    int e = ebase + e0;
    float w = ew[e];
    if (w != 0.0f) {
      int s = src[e], d = dst[e];
      float nrm = rsqrtf(deg[s]) * rsqrtf(deg[d]);   // w == 1 when valid
      float val = xw[(size_t)s * HID + c0 + c] * nrm;
      atomicAdd(&acc[(d - nbase) * 16 + c], val);
    }
  }
  __syncthreads();
  for (int i = t; i < nf; i += 256) {
    int v = i >> 4, cc = i & 15;
    h[(size_t)(nbase + v) * HID + c0 + cc] = acc[i];
  }
}

// ---------------- h = agg + xw/deg + b ; accumulate BN sums ----------------
__global__ __launch_bounds__(256) void h_finalize(
    const float* __restrict__ xw, const float* __restrict__ deg,
    const float* __restrict__ bias, float* __restrict__ h,
    float* __restrict__ sums, int n_nodes) {
  __shared__ float4 redS[16][16];
  __shared__ float4 redQ[16][16];
  int t = threadIdx.x;
  int cq = t & 15, ng = t >> 4;
  int c4 = cq * 4;
  float4 bv = *(const float4*)(bias + c4);
  float4 S = make_float4(0, 0, 0, 0), Q = make_float4(0, 0, 0, 0);
  for (int node = blockIdx.x * 16 + ng; node < n_nodes; node += gridDim.x * 16) {
    float di2 = 1.0f / deg[node];
    float4 xv = *(const float4*)(xw + (size_t)node * HID + c4);
    float4* hp = (float4*)(h + (size_t)node * HID + c4);
    float4 hv = *hp;
    hv.x += xv.x * di2 + bv.x;
    hv.y += xv.y * di2 + bv.y;
    hv.z += xv.z * di2 + bv.z;
    hv.w += xv.w * di2 + bv.w;
    *hp = hv;
    S.x += hv.x; S.y += hv.y; S.z += hv.z; S.w += hv.w;
    Q.x += hv.x * hv.x; Q.y += hv.y * hv.y; Q.z += hv.z * hv.z; Q.w += hv.w * hv.w;
  }
  redS[ng][cq] = S; redQ[ng][cq] = Q;
  __syncthreads();
  if (t < 16) {
    float4 aS = redS[0][t], aQ = redQ[0][t];
    for (int gg = 1; gg < 16; gg++) {
      float4 s2 = redS[gg][t], q2 = redQ[gg][t];
      aS.x += s2.x; aS.y += s2.y; aS.z += s2.z; aS.w += s2.w;
      aQ.x += q2.x; aQ.y += q2.y; aQ.z += q2.z; aQ.w += q2.w;
    }
    atomicAdd(&sums[t * 4 + 0], aS.x);
    atomicAdd(&sums[t * 4 + 1], aS.y);
    atomicAdd(&sums[t * 4 + 2], aS.z);
    atomicAdd(&sums[t * 4 + 3], aS.w);
    atomicAdd(&sums[64 + t * 4 + 0], aQ.x);
    atomicAdd(&sums[64 + t * 4 + 1], aQ.y);
    atomicAdd(&sums[64 + t * 4 + 2], aQ.z);
    atomicAdd(&sums[64 + t * 4 + 3], aQ.w);
  }
}

// ---------------- BN(train) + ReLU in-place + score = y.p/||p|| ----------------
__global__ __launch_bounds__(256) void bn_relu_score(
    float* __restrict__ h, const float* __restrict__ sums,
    const float* __restrict__ gamma, const float* __restrict__ beta,
    const float* __restrict__ p, float* __restrict__ score,
    int n_nodes, float inv_n) {
  __shared__ float sSc[HID], sSh[HID], sP[HID];
  __shared__ float invPn;
  int t = threadIdx.x;
  if (t < HID) {
    float mu = sums[t] * inv_n;
    float var = fmaxf(sums[64 + t] * inv_n - mu * mu, 0.0f);
    float sc = rsqrtf(var + 1e-5f) * gamma[t];
    sSc[t] = sc;
    sSh[t] = beta[t] - mu * sc;
    sP[t] = p[t];
  }
  __syncthreads();
  if (t == 0) {
    float s = 0.0f;
    for (int i = 0; i < HID; i++) s += sP[i] * sP[i];
    invPn = rsqrtf(s);
  }
  __syncthreads();
  int idx = blockIdx.x * 256 + t;
  int node = idx >> 2;
  if (node >= n_nodes) return;
  int seg = (idx & 3) * 16;
  float* hp = h + (size_t)node * HID + seg;
  float sacc = 0.0f;
#pragma unroll
  for (int q = 0; q < 4; q++) {
    float4 v = *(float4*)(hp + q * 4);
    int ch = seg + q * 4;
    v.x = fmaxf(fmaf(v.x, sSc[ch + 0], sSh[ch + 0]), 0.0f);
    v.y = fmaxf(fmaf(v.y, sSc[ch + 1], sSh[ch + 1]), 0.0f);
    v.z = fmaxf(fmaf(v.z, sSc[ch + 2], sSh[ch + 2]), 0.0f);
    v.w = fmaxf(fmaf(v.w, sSc[ch + 3], sSh[ch + 3]), 0.0f);
    sacc += v.x * sP[ch + 0] + v.y * sP[ch + 1] + v.z * sP[ch + 2] + v.w * sP[ch + 3];
    *(float4*)(hp + q * 4) = v;
  }
  sacc += __shfl_xor(sacc, 1);
  sacc += __shfl_xor(sacc, 2);
  if ((idx & 3) == 0) score[node] = sacc * invPn;
}

// ---------------- per-graph top-k by rank counting ----------------
__global__ __launch_bounds__(256) void topk_kernel(
    const float* __restrict__ score, int* __restrict__ mapping,
    int* __restrict__ oon, int npg, int k) {
  __shared__ float s[1024];
  int b = blockIdx.x, t = threadIdx.x;
  const float* sc = score + (size_t)b * npg;
#pragma unroll
  for (int m = 0; m < 4; m++) {
    int i = t * 4 + m;
    s[i] = (i < npg) ? sc[i] : -INFINITY;
  }
  __syncthreads();
  float my[4]; int r[4];
#pragma unroll
  for (int m = 0; m < 4; m++) { my[m] = s[t * 4 + m]; r[m] = 0; }
  for (int jb = 0; jb < 256; jb++) {
    float4 v = ((const float4*)s)[jb];
    int j0 = jb * 4;
#pragma unroll
    for (int m = 0; m < 4; m++) {
      int gi = t * 4 + m;
      r[m] += (v.x > my[m]) || (v.x == my[m] && (j0 + 0) < gi);
      r[m] += (v.y > my[m]) || (v.y == my[m] && (j0 + 1) < gi);
      r[m] += (v.z > my[m]) || (v.z == my[m] && (j0 + 2) < gi);
      r[m] += (v.w > my[m]) || (v.w == my[m] && (j0 + 3) < gi);
    }
  }
#pragma unroll
  for (int m = 0; m < 4; m++) {
    int i = t * 4 + m;
    if (i < npg && r[m] < k) {
      mapping[(size_t)b * npg + i] = b * k + r[m];
      oon[b * k + r[m]] = b * npg + i;
    }
  }
}

// ---------------- gather pooled x (*tanh(score)) + mean/max readout ----------------
__global__ __launch_bounds__(256) void pool_readout(
    const float* __restrict__ y, const float* __restrict__ score,
    const int* __restrict__ oon, float* __restrict__ xpool,
    float* __restrict__ readout, int k) {
  __shared__ float4 rS[16][16];
  __shared__ float4 rM[16][16];
  int b = blockIdx.x, t = threadIdx.x;
  int cq = t & 15, ng = t >> 4;
  int c4 = cq * 4;
  float4 S = make_float4(0, 0, 0, 0);
  float4 M = make_float4(-INFINITY, -INFINITY, -INFINITY, -INFINITY);
  for (int j = ng; j < k; j += 16) {
    int newg = b * k + j;
    int old = oon[newg];
    float tn = tanhf(score[old]);
    float4 v = *(const float4*)(y + (size_t)old * HID + c4);
    v.x *= tn; v.y *= tn; v.z *= tn; v.w *= tn;
    if (xpool != nullptr) *(float4*)(xpool + (size_t)newg * HID + c4) = v;
    S.x += v.x; S.y += v.y; S.z += v.z; S.w += v.w;
    M.x = fmaxf(M.x, v.x); M.y = fmaxf(M.y, v.y);
    M.z = fmaxf(M.z, v.z); M.w = fmaxf(M.w, v.w);
  }
  rS[ng][cq] = S; rM[ng][cq] = M;
  __syncthreads();
  if (t < 16) {
    float4 aS = rS[0][t], aM = rM[0][t];
    for (int gg = 1; gg < 16; gg++) {
      float4 s2 = rS[gg][t], m2 = rM[gg][t];
      aS.x += s2.x; aS.y += s2.y; aS.z += s2.z; aS.w += s2.w;
      aM.x = fmaxf(aM.x, m2.x); aM.y = fmaxf(aM.y, m2.y);
      aM.z = fmaxf(aM.z, m2.z); aM.w = fmaxf(aM.w, m2.w);
    }
    float invk = 1.0f / (float)k;
    float* ro = readout + (size_t)b * 2 * HID;
    ro[t * 4 + 0] += aS.x * invk;
    ro[t * 4 + 1] += aS.y * invk;
    ro[t * 4 + 2] += aS.z * invk;
    ro[t * 4 + 3] += aS.w * invk;
    ro[HID + t * 4 + 0] += aM.x;
    ro[HID + t * 4 + 1] += aM.y;
    ro[HID + t * 4 + 2] += aM.z;
    ro[HID + t * 4 + 3] += aM.w;
  }
}

// ---------------- edge re-index through mapping (in-place safe) ----------------
__global__ __launch_bounds__(256) void remap_edges(
    const int* __restrict__ src_in, const int* __restrict__ dst_in,
    const float* __restrict__ ew_in, const int* __restrict__ mapping,
    int* __restrict__ src_out, int* __restrict__ dst_out,
    float* __restrict__ ew_out) {
  int e = blockIdx.x * 256 + threadIdx.x;  // grid sized exactly
  int s = src_in[e], d = dst_in[e];
  float w = ew_in[e];
  int ns = mapping[s], nd = mapping[d];
  bool valid = (ns >= 0) && (nd >= 0) && (w > 0.0f);
  src_out[e] = valid ? ns : 0;
  dst_out[e] = valid ? nd : 0;
  ew_out[e] = valid ? 1.0f : 0.0f;
}

// ---------------- out = readout @ Wm + bm ----------------
__global__ __launch_bounds__(256) void final_linear(
    const float* __restrict__ readout, const float* __restrict__ Wm,
    const float* __restrict__ bm, float* __restrict__ out) {
  int idx = blockIdx.x * 256 + threadIdx.x;
  if (idx >= NGR * 10) return;
  int b = idx / 10, o = idx - b * 10;
  float acc = bm[o];
  const float* r = readout + (size_t)b * 2 * HID;
  for (int c = 0; c < 2 * HID; c++) acc = fmaf(r[c], Wm[c * 10 + o], acc);
  out[idx] = acc;
}

extern "C" void kernel_launch(void* const* d_in, const int* in_sizes, int n_in,
                              void* d_out, int out_size, void* d_ws, size_t ws_size,
                              hipStream_t stream) {
  (void)in_sizes; (void)n_in; (void)out_size; (void)ws_size;
  const float* x  = (const float*)d_in[0];
  const int*   ei = (const int*)d_in[1];
  const float* Wk[3]  = {(const float*)d_in[2],  (const float*)d_in[7],  (const float*)d_in[12]};
  const float* bk[3]  = {(const float*)d_in[3],  (const float*)d_in[8],  (const float*)d_in[13]};
  const float* gk[3]  = {(const float*)d_in[4],  (const float*)d_in[9],  (const float*)d_in[14]};
  const float* btk[3] = {(const float*)d_in[5],  (const float*)d_in[10], (const float*)d_in[15]};
  const float* pk[3]  = {(const float*)d_in[6],  (const float*)d_in[11], (const float*)d_in[16]};
  const float* Wm = (const float*)d_in[17];
  const float* bm = (const float*)d_in[18];
  float* out = (float*)d_out;

  // ---- workspace carve (floats) ----
  float* ws = (float*)d_ws;
  size_t off = 0;
  auto alloc = [&](size_t nfl) {
    float* ptr = ws + off;
    off += (nfl + 63) & ~(size_t)63;
    return ptr;
  };
  float* bufA = alloc((size_t)131072 * 64);   // xw blk1/2; pool2 out
  float* bufB = alloc((size_t)131072 * 64);   // h / y all blocks
  float* bufC = alloc((size_t)104960 * 64);   // pool1 out; xw blk3
  float* deg  = alloc(131072);
  float* score = alloc(131072);
  int*   mapping = (int*)alloc(131072);
  int*   oon     = (int*)alloc(105024);
  int*   srcB = (int*)alloc(EDGES);
  int*   dstB = (int*)alloc(EDGES);
  float* ewB  = alloc(EDGES);
  float* ew1  = alloc(EDGES);
  float* sums = alloc(128);                   // [0:64] sum, [64:128] sumsq
  float* readout = alloc(NGR * 2 * HID);

  // =============== Block 1: n=1024 -> k=820 ===============
  {
    const int npg = 1024, k = 820, Nc = NGR * npg;   // 131072
    fill_kernel<<<1024, 256, 0, stream>>>(deg, mapping, Nc, sums, ew1, readout, EDGES);
    gemm_xw<128><<<Nc / 128, 256, 0, stream>>>(x, Wk[0], bufA, Nc);
    deg_acc<<<EDGES / 256, 256, 0, stream>>>(ei + EDGES, ew1, deg);
    edge_agg<<<NGR * 4, 256, 0, stream>>>(ei, ei + EDGES, ew1, deg, bufA, bufB, npg);
    h_finalize<<<512, 256, 0, stream>>>(bufA, deg, bk[0], bufB, sums, Nc);
    bn_relu_score<<<Nc * 4 / 256, 256, 0, stream>>>(bufB, sums, gk[0], btk[0], pk[0],
                                                    score, Nc, 1.0f / Nc);
    topk_kernel<<<NGR, 256, 0, stream>>>(score, mapping, oon, npg, k);
    pool_readout<<<NGR, 256, 0, stream>>>(bufB, score, oon, bufC, readout, k);
    remap_edges<<<EDGES / 256, 256, 0, stream>>>(ei, ei + EDGES, ew1, mapping,
                                                 srcB, dstB, ewB);
  }
  // =============== Block 2: n=820 -> k=656 ===============
  {
    const int npg = 820, k = 656, Nc = NGR * npg;    // 104960
    fill_kernel<<<512, 256, 0, stream>>>(deg, mapping, Nc, sums, nullptr, nullptr, Nc);
    gemm_xw<64><<<Nc / 128, 256, 0, stream>>>(bufC, Wk[1], bufA, Nc);
    deg_acc<<<EDGES / 256, 256, 0, stream>>>(dstB, ewB, deg);
    edge_agg<<<NGR * 4, 256, 0, stream>>>(srcB, dstB, ewB, deg, bufA, bufB, npg);
    h_finalize<<<512, 256, 0, stream>>>(bufA, deg, bk[1], bufB, sums, Nc);
    bn_relu_score<<<Nc * 4 / 256, 256, 0, stream>>>(bufB, sums, gk[1], btk[1], pk[1],
                                                    score, Nc, 1.0f / Nc);
    topk_kernel<<<NGR, 256, 0, stream>>>(score, mapping, oon, npg, k);
    pool_readout<<<NGR, 256, 0, stream>>>(bufB, score, oon, bufA, readout, k);
    remap_edges<<<EDGES / 256, 256, 0, stream>>>(srcB, dstB, ewB, mapping,
                                                 srcB, dstB, ewB);  // in-place safe
  }
  // =============== Block 3: n=656 -> k=525 ===============
  {
    const int npg = 656, k = 525, Nc = NGR * npg;    // 83968
    fill_kernel<<<512, 256, 0, stream>>>(deg, mapping, Nc, sums, nullptr, nullptr, Nc);
    gemm_xw<64><<<Nc / 128, 256, 0, stream>>>(bufA, Wk[2], bufC, Nc);
    deg_acc<<<EDGES / 256, 256, 0, stream>>>(dstB, ewB, deg);
    edge_agg<<<NGR * 4, 256, 0, stream>>>(srcB, dstB, ewB, deg, bufC, bufB, npg);
    h_finalize<<<512, 256, 0, stream>>>(bufC, deg, bk[2], bufB, sums, Nc);
    bn_relu_score<<<Nc * 4 / 256, 256, 0, stream>>>(bufB, sums, gk[2], btk[2], pk[2],
                                                    score, Nc, 1.0f / Nc);
    topk_kernel<<<NGR, 256, 0, stream>>>(score, mapping, oon, npg, k);
    pool_readout<<<NGR, 256, 0, stream>>>(bufB, score, oon, nullptr, readout, k);
  }
  final_linear<<<5, 256, 0, stream>>>(readout, Wm, bm, out);
}

// Round 2
// 1459.159 us; speedup vs baseline: 1.3873x; 1.3873x over previous
//
#include <hip/hip_runtime.h>
#include <cmath>
#include <cstdint>
#include <cstddef>

#define HID 64
#define NGR 128            // B graphs
#define EDGES 1048576      // B * 1024 * 8
#define EPG 8192           // edges per graph
#define VALID (1u << 20)

// ---------------- pack edges to graph-local u32 + zero sums/readout ----------------
__global__ __launch_bounds__(256) void pack_init(
    const int* __restrict__ ei, uint32_t* __restrict__ packed,
    float* __restrict__ sums3, float* __restrict__ readout) {
  int i0 = blockIdx.x * 256 + threadIdx.x;
  int stride = gridDim.x * 256;
  for (int e = i0; e < EDGES; e += stride) {
    int g = e >> 13;                       // 8192 edges per graph
    int base = g << 10;
    uint32_t s = (uint32_t)(ei[e] - base);
    uint32_t d = (uint32_t)(ei[EDGES + e] - base);
    packed[e] = s | (d << 10) | VALID;
  }
  if (i0 < 3 * 128) sums3[i0] = 0.0f;
  if (i0 < NGR * 2 * HID) readout[i0] = 0.0f;
}

// ---------------- per-graph degree -> dinv = rsqrt(deg+1) ----------------
__global__ __launch_bounds__(256) void deg_kernel(
    const uint32_t* __restrict__ packed, float* __restrict__ dinv_g, int npg) {
  __shared__ int hist[1024];
  int b = blockIdx.x, t = threadIdx.x;
  for (int i = t; i < npg; i += 256) hist[i] = 0;
  __syncthreads();
  const uint32_t* pe = packed + (size_t)b * EPG;
  for (int e = t; e < EPG; e += 256) {
    uint32_t pk = pe[e];
    if (pk & VALID) atomicAdd(&hist[(pk >> 10) & 1023], 1);
  }
  __syncthreads();
  for (int i = t; i < npg; i += 256)
    dinv_g[(size_t)b * npg + i] = rsqrtf((float)hist[i] + 1.0f);
}

// ---------------- xw = X @ W  (X:[N,DIN], W:[DIN,64]) ----------------
template<int DIN>
__global__ __launch_bounds__(256) void gemm_xw(
    const float* __restrict__ X, const float* __restrict__ W,
    float* __restrict__ XW, int n_nodes) {
  __shared__ float sW[32 * HID];       // 8 KB
  __shared__ float sXT[32 * 132];      // 16.5 KB
  const int t = threadIdx.x;
  const int cq = t & 15, ng = t >> 4;
  const int c4 = cq * 4;
  const int node0 = blockIdx.x * 128;
  float acc[8][4];
#pragma unroll
  for (int n = 0; n < 8; n++) { acc[n][0]=0.f; acc[n][1]=0.f; acc[n][2]=0.f; acc[n][3]=0.f; }

  for (int k0 = 0; k0 < DIN; k0 += 32) {
    ((float4*)sW)[t * 2 + 0] = ((const float4*)(W + (size_t)k0 * HID))[t * 2 + 0];
    ((float4*)sW)[t * 2 + 1] = ((const float4*)(W + (size_t)k0 * HID))[t * 2 + 1];
    {
      int i4 = (t & 7) * 4;
      int nl = t >> 3;
#pragma unroll
      for (int rep = 0; rep < 4; rep++) {
        int nn = nl + rep * 32;
        int g = node0 + nn;
        float4 v = make_float4(0.f, 0.f, 0.f, 0.f);
        if (g < n_nodes) v = *(const float4*)(X + (size_t)g * DIN + k0 + i4);
        sXT[(i4 + 0) * 132 + nn] = v.x;
        sXT[(i4 + 1) * 132 + nn] = v.y;
        sXT[(i4 + 2) * 132 + nn] = v.z;
        sXT[(i4 + 3) * 132 + nn] = v.w;
      }
    }
    __syncthreads();
#pragma unroll 4
    for (int i = 0; i < 32; i++) {
      float4 w = *(const float4*)(sW + i * HID + c4);
      const float* xr = sXT + i * 132 + ng * 8;
      float4 xa = *(const float4*)xr;
      float4 xb = *(const float4*)(xr + 4);
      float xn[8] = {xa.x, xa.y, xa.z, xa.w, xb.x, xb.y, xb.z, xb.w};
#pragma unroll
      for (int n = 0; n < 8; n++) {
        acc[n][0] = fmaf(xn[n], w.x, acc[n][0]);
        acc[n][1] = fmaf(xn[n], w.y, acc[n][1]);
        acc[n][2] = fmaf(xn[n], w.z, acc[n][2]);
        acc[n][3] = fmaf(xn[n], w.w, acc[n][3]);
      }
    }
    __syncthreads();
  }
#pragma unroll
  for (int n = 0; n < 8; n++) {
    int g = node0 + ng * 8 + n;
    if (g < n_nodes)
      *(float4*)(XW + (size_t)g * HID + c4) =
          make_float4(acc[n][0], acc[n][1], acc[n][2], acc[n][3]);
  }
}

// ---------------- fused: aggregate + self-loop + bias + BN partial sums ----------------
// block = (channel-eighth q) * 128 + (graph g)  -> all 8 splits of g on XCD g%8
__global__ __launch_bounds__(256) void edge_agg(
    const uint32_t* __restrict__ packed, const float* __restrict__ dinv_g,
    const float* __restrict__ xw, const float* __restrict__ bias,
    float* __restrict__ h, float* __restrict__ sums, int npg) {
  __shared__ float xw_s[1024 * 8];   // 32 KB
  __shared__ float acc[1024 * 8];    // 32 KB
  __shared__ float dinv[1024];       // 4 KB
  __shared__ float4 sredS[4][2];
  __shared__ float4 sredQ[4][2];
  int g = blockIdx.x & 127;
  int q = blockIdx.x >> 7;
  int t = threadIdx.x;
  int c0 = q * 8;

  for (int i = t; i < npg; i += 256) dinv[i] = dinv_g[(size_t)g * npg + i];
  for (int i = t; i < npg * 2; i += 256) {
    int node = i >> 1, half = i & 1;
    float4 v = *(const float4*)(xw + (size_t)(g * npg + node) * HID + c0 + half * 4);
    *(float4*)(xw_s + node * 8 + half * 4) = v;
    *(float4*)(acc + node * 8 + half * 4) = make_float4(0, 0, 0, 0);
  }
  __syncthreads();

  int c = t & 7, j = t >> 3;          // 32 edges per block-iter
  const uint32_t* pe = packed + (size_t)g * EPG;
  for (int e = j; e < EPG; e += 32) {
    uint32_t pk = pe[e];
    if (pk & VALID) {
      int s = pk & 1023, d = (pk >> 10) & 1023;
      float nrm = dinv[s] * dinv[d];
      atomicAdd(&acc[d * 8 + c], xw_s[s * 8 + c] * nrm);
    }
  }
  __syncthreads();

  float4 bv0 = *(const float4*)(bias + c0);
  float4 bv1 = *(const float4*)(bias + c0 + 4);
  float4 S = make_float4(0, 0, 0, 0), Q = make_float4(0, 0, 0, 0);
  for (int i = t; i < npg * 2; i += 256) {
    int node = i >> 1, half = i & 1;
    float di = dinv[node];
    float d2 = di * di;
    float4 a = *(float4*)(acc + node * 8 + half * 4);
    float4 xv = *(float4*)(xw_s + node * 8 + half * 4);
    float4 bv = half ? bv1 : bv0;
    a.x += xv.x * d2 + bv.x;
    a.y += xv.y * d2 + bv.y;
    a.z += xv.z * d2 + bv.z;
    a.w += xv.w * d2 + bv.w;
    *(float4*)(h + (size_t)(g * npg + node) * HID + c0 + half * 4) = a;
    S.x += a.x; S.y += a.y; S.z += a.z; S.w += a.w;
    Q.x += a.x * a.x; Q.y += a.y * a.y; Q.z += a.z * a.z; Q.w += a.w * a.w;
  }
  // reduce over lanes of same parity (channel-half fixed per thread: t&1)
#pragma unroll
  for (int m = 2; m < 64; m <<= 1) {
    S.x += __shfl_xor(S.x, m); S.y += __shfl_xor(S.y, m);
    S.z += __shfl_xor(S.z, m); S.w += __shfl_xor(S.w, m);
    Q.x += __shfl_xor(Q.x, m); Q.y += __shfl_xor(Q.y, m);
    Q.z += __shfl_xor(Q.z, m); Q.w += __shfl_xor(Q.w, m);
  }
  int lane = t & 63, wv = t >> 6;
  if (lane < 2) { sredS[wv][lane] = S; sredQ[wv][lane] = Q; }
  __syncthreads();
  if (t < 2) {
    float4 aS = sredS[0][t], aQ = sredQ[0][t];
    for (int w = 1; w < 4; w++) {
      float4 s2 = sredS[w][t], q2 = sredQ[w][t];
      aS.x += s2.x; aS.y += s2.y; aS.z += s2.z; aS.w += s2.w;
      aQ.x += q2.x; aQ.y += q2.y; aQ.z += q2.z; aQ.w += q2.w;
    }
    int cb = c0 + t * 4;
    atomicAdd(&sums[cb + 0], aS.x);
    atomicAdd(&sums[cb + 1], aS.y);
    atomicAdd(&sums[cb + 2], aS.z);
    atomicAdd(&sums[cb + 3], aS.w);
    atomicAdd(&sums[64 + cb + 0], aQ.x);
    atomicAdd(&sums[64 + cb + 1], aQ.y);
    atomicAdd(&sums[64 + cb + 2], aQ.z);
    atomicAdd(&sums[64 + cb + 3], aQ.w);
  }
}

// ---------------- BN(train) + ReLU in-place + score = y.p/||p|| ----------------
__global__ __launch_bounds__(256) void bn_relu_score(
    float* __restrict__ h, const float* __restrict__ sums,
    const float* __restrict__ gamma, const float* __restrict__ beta,
    const float* __restrict__ p, float* __restrict__ score,
    int n_nodes, float inv_n) {
  __shared__ float sSc[HID], sSh[HID], sP[HID];
  __shared__ float invPn;
  int t = threadIdx.x;
  if (t < HID) {
    float mu = sums[t] * inv_n;
    float var = fmaxf(sums[64 + t] * inv_n - mu * mu, 0.0f);
    float sc = rsqrtf(var + 1e-5f) * gamma[t];
    sSc[t] = sc;
    sSh[t] = beta[t] - mu * sc;
    sP[t] = p[t];
  }
  __syncthreads();
  if (t == 0) {
    float s = 0.0f;
    for (int i = 0; i < HID; i++) s += sP[i] * sP[i];
    invPn = rsqrtf(s);
  }
  __syncthreads();
  int idx = blockIdx.x * 256 + t;
  int node = idx >> 2;
  if (node >= n_nodes) return;
  int seg = (idx & 3) * 16;
  float* hp = h + (size_t)node * HID + seg;
  float sacc = 0.0f;
#pragma unroll
  for (int q = 0; q < 4; q++) {
    float4 v = *(float4*)(hp + q * 4);
    int ch = seg + q * 4;
    v.x = fmaxf(fmaf(v.x, sSc[ch + 0], sSh[ch + 0]), 0.0f);
    v.y = fmaxf(fmaf(v.y, sSc[ch + 1], sSh[ch + 1]), 0.0f);
    v.z = fmaxf(fmaf(v.z, sSc[ch + 2], sSh[ch + 2]), 0.0f);
    v.w = fmaxf(fmaf(v.w, sSc[ch + 3], sSh[ch + 3]), 0.0f);
    sacc += v.x * sP[ch + 0] + v.y * sP[ch + 1] + v.z * sP[ch + 2] + v.w * sP[ch + 3];
    *(float4*)(hp + q * 4) = v;
  }
  sacc += __shfl_xor(sacc, 1);
  sacc += __shfl_xor(sacc, 2);
  if ((idx & 3) == 0) score[node] = sacc * invPn;
}

// ---------------- per-graph top-k by rank counting (writes FULL local mapping) ----------------
__global__ __launch_bounds__(256) void topk_kernel(
    const float* __restrict__ score, int* __restrict__ mapping,
    int* __restrict__ oon, int npg, int k) {
  __shared__ float s[1024];
  int b = blockIdx.x, t = threadIdx.x;
  const float* sc = score + (size_t)b * npg;
#pragma unroll
  for (int m = 0; m < 4; m++) {
    int i = t * 4 + m;
    s[i] = (i < npg) ? sc[i] : -INFINITY;
  }
  __syncthreads();
  float my[4]; int r[4];
#pragma unroll
  for (int m = 0; m < 4; m++) { my[m] = s[t * 4 + m]; r[m] = 0; }
  for (int jb = 0; jb < 256; jb++) {
    float4 v = ((const float4*)s)[jb];
    int j0 = jb * 4;
#pragma unroll
    for (int m = 0; m < 4; m++) {
      int gi = t * 4 + m;
      r[m] += (v.x > my[m]) || (v.x == my[m] && (j0 + 0) < gi);
      r[m] += (v.y > my[m]) || (v.y == my[m] && (j0 + 1) < gi);
      r[m] += (v.z > my[m]) || (v.z == my[m] && (j0 + 2) < gi);
      r[m] += (v.w > my[m]) || (v.w == my[m] && (j0 + 3) < gi);
    }
  }
#pragma unroll
  for (int m = 0; m < 4; m++) {
    int i = t * 4 + m;
    if (i < npg) {
      mapping[(size_t)b * npg + i] = (r[m] < k) ? r[m] : -1;   // LOCAL new idx
      if (r[m] < k) oon[b * k + r[m]] = b * npg + i;           // global old idx
    }
  }
}

// ---------------- gather pooled x (*tanh(score)) + mean/max readout ----------------
__global__ __launch_bounds__(256) void pool_readout(
    const float* __restrict__ y, const float* __restrict__ score,
    const int* __restrict__ oon, float* __restrict__ xpool,
    float* __restrict__ readout, int k) {
  __shared__ float4 rS[16][16];
  __shared__ float4 rM[16][16];
  int b = blockIdx.x, t = threadIdx.x;
  int cq = t & 15, ng = t >> 4;
  int c4 = cq * 4;
  float4 S = make_float4(0, 0, 0, 0);
  float4 M = make_float4(-INFINITY, -INFINITY, -INFINITY, -INFINITY);
  for (int j = ng; j < k; j += 16) {
    int newg = b * k + j;
    int old = oon[newg];
    float tn = tanhf(score[old]);
    float4 v = *(const float4*)(y + (size_t)old * HID + c4);
    v.x *= tn; v.y *= tn; v.z *= tn; v.w *= tn;
    if (xpool != nullptr) *(float4*)(xpool + (size_t)newg * HID + c4) = v;
    S.x += v.x; S.y += v.y; S.z += v.z; S.w += v.w;
    M.x = fmaxf(M.x, v.x); M.y = fmaxf(M.y, v.y);
    M.z = fmaxf(M.z, v.z); M.w = fmaxf(M.w, v.w);
  }
  rS[ng][cq] = S; rM[ng][cq] = M;
  __syncthreads();
  if (t < 16) {
    float4 aS = rS[0][t], aM = rM[0][t];
    for (int gg = 1; gg < 16; gg++) {
      float4 s2 = rS[gg][t], m2 = rM[gg][t];
      aS.x += s2.x; aS.y += s2.y; aS.z += s2.z; aS.w += s2.w;
      aM.x = fmaxf(aM.x, m2.x); aM.y = fmaxf(aM.y, m2.y);
      aM.z = fmaxf(aM.z, m2.z); aM.w = fmaxf(aM.w, m2.w);
    }
    float invk = 1.0f / (float)k;
    float* ro = readout + (size_t)b * 2 * HID;
    ro[t * 4 + 0] += aS.x * invk;
    ro[t * 4 + 1] += aS.y * invk;
    ro[t * 4 + 2] += aS.z * invk;
    ro[t * 4 + 3] += aS.w * invk;
    ro[HID + t * 4 + 0] += aM.x;
    ro[HID + t * 4 + 1] += aM.y;
    ro[HID + t * 4 + 2] += aM.z;
    ro[HID + t * 4 + 3] += aM.w;
  }
}

// ---------------- per-graph edge remap through LDS mapping table ----------------
__global__ __launch_bounds__(256) void remap_edges(
    uint32_t* __restrict__ packed, const int* __restrict__ mapping, int npg) {
  __shared__ int lmap[1024];
  int b = blockIdx.x, t = threadIdx.x;
  for (int i = t; i < npg; i += 256) lmap[i] = mapping[(size_t)b * npg + i];
  __syncthreads();
  uint32_t* pe = packed + (size_t)b * EPG;
  for (int e = t; e < EPG; e += 256) {
    uint32_t pk = pe[e];
    uint32_t out = 0;
    if (pk & VALID) {
      int ns = lmap[pk & 1023], nd = lmap[(pk >> 10) & 1023];
      if (ns >= 0 && nd >= 0)
        out = (uint32_t)ns | ((uint32_t)nd << 10) | VALID;
    }
    pe[e] = out;
  }
}

// ---------------- out = readout @ Wm + bm ----------------
__global__ __launch_bounds__(256) void final_linear(
    const float* __restrict__ readout, const float* __restrict__ Wm,
    const float* __restrict__ bm, float* __restrict__ out) {
  int idx = blockIdx.x * 256 + threadIdx.x;
  if (idx >= NGR * 10) return;
  int b = idx / 10, o = idx - b * 10;
  float acc = bm[o];
  const float* r = readout + (size_t)b * 2 * HID;
  for (int c = 0; c < 2 * HID; c++) acc = fmaf(r[c], Wm[c * 10 + o], acc);
  out[idx] = acc;
}

extern "C" void kernel_launch(void* const* d_in, const int* in_sizes, int n_in,
                              void* d_out, int out_size, void* d_ws, size_t ws_size,
                              hipStream_t stream) {
  (void)in_sizes; (void)n_in; (void)out_size; (void)ws_size;
  const float* x  = (const float*)d_in[0];
  const int*   ei = (const int*)d_in[1];
  const float* Wk[3]  = {(const float*)d_in[2],  (const float*)d_in[7],  (const float*)d_in[12]};
  const float* bk[3]  = {(const float*)d_in[3],  (const float*)d_in[8],  (const float*)d_in[13]};
  const float* gk[3]  = {(const float*)d_in[4],  (const float*)d_in[9],  (const float*)d_in[14]};
  const float* btk[3] = {(const float*)d_in[5],  (const float*)d_in[10], (const float*)d_in[15]};
  const float* pk[3]  = {(const float*)d_in[6],  (const float*)d_in[11], (const float*)d_in[16]};
  const float* Wm = (const float*)d_in[17];
  const float* bm = (const float*)d_in[18];
  float* out = (float*)d_out;

  // ---- workspace carve (floats) ----
  float* ws = (float*)d_ws;
  size_t off = 0;
  auto alloc = [&](size_t nfl) {
    float* ptr = ws + off;
    off += (nfl + 63) & ~(size_t)63;
    return ptr;
  };
  float* bufA = alloc((size_t)131072 * 64);   // xw blk1/2; pool2 out
  float* bufB = alloc((size_t)131072 * 64);   // h / y all blocks
  float* bufC = alloc((size_t)104960 * 64);   // pool1 out; xw blk3
  float* dinv_g = alloc(131072);
  float* score  = alloc(131072);
  int*   mapping = (int*)alloc(131072);
  int*   oon     = (int*)alloc(105024);
  uint32_t* packed = (uint32_t*)alloc(EDGES);
  float* sums3 = alloc(3 * 128);
  float* readout = alloc(NGR * 2 * HID);

  // =============== Block 1: n=1024 -> k=820 ===============
  {
    const int npg = 1024, k = 820, Nc = NGR * npg;   // 131072
    pack_init<<<1024, 256, 0, stream>>>(ei, packed, sums3, readout);
    gemm_xw<128><<<Nc / 128, 256, 0, stream>>>(x, Wk[0], bufA, Nc);
    deg_kernel<<<NGR, 256, 0, stream>>>(packed, dinv_g, npg);
    edge_agg<<<NGR * 8, 256, 0, stream>>>(packed, dinv_g, bufA, bk[0], bufB,
                                          sums3, npg);
    bn_relu_score<<<Nc * 4 / 256, 256, 0, stream>>>(bufB, sums3, gk[0], btk[0],
                                                    pk[0], score, Nc, 1.0f / Nc);
    topk_kernel<<<NGR, 256, 0, stream>>>(score, mapping, oon, npg, k);
    pool_readout<<<NGR, 256, 0, stream>>>(bufB, score, oon, bufC, readout, k);
    remap_edges<<<NGR, 256, 0, stream>>>(packed, mapping, npg);
  }
  // =============== Block 2: n=820 -> k=656 ===============
  {
    const int npg = 820, k = 656, Nc = NGR * npg;    // 104960
    gemm_xw<64><<<Nc / 128, 256, 0, stream>>>(bufC, Wk[1], bufA, Nc);
    deg_kernel<<<NGR, 256, 0, stream>>>(packed, dinv_g, npg);
    edge_agg<<<NGR * 8, 256, 0, stream>>>(packed, dinv_g, bufA, bk[1], bufB,
                                          sums3 + 128, npg);
    bn_relu_score<<<Nc * 4 / 256, 256, 0, stream>>>(bufB, sums3 + 128, gk[1], btk[1],
                                                    pk[1], score, Nc, 1.0f / Nc);
    topk_kernel<<<NGR, 256, 0, stream>>>(score, mapping, oon, npg, k);
    pool_readout<<<NGR, 256, 0, stream>>>(bufB, score, oon, bufA, readout, k);
    remap_edges<<<NGR, 256, 0, stream>>>(packed, mapping, npg);
  }
  // =============== Block 3: n=656 -> k=525 ===============
  {
    const int npg = 656, k = 525, Nc = NGR * npg;    // 83968
    gemm_xw<64><<<Nc / 128, 256, 0, stream>>>(bufA, Wk[2], bufC, Nc);
    deg_kernel<<<NGR, 256, 0, stream>>>(packed, dinv_g, npg);
    edge_agg<<<NGR * 8, 256, 0, stream>>>(packed, dinv_g, bufC, bk[2], bufB,
                                          sums3 + 256, npg);
    bn_relu_score<<<Nc * 4 / 256, 256, 0, stream>>>(bufB, sums3 + 256, gk[2], btk[2],
                                                    pk[2], score, Nc, 1.0f / Nc);
    topk_kernel<<<NGR, 256, 0, stream>>>(score, mapping, oon, npg, k);
    pool_readout<<<NGR, 256, 0, stream>>>(bufB, score, oon, nullptr, readout, k);
  }
  final_linear<<<5, 256, 0, stream>>>(readout, Wm, bm, out);
}